// Round 5
// baseline (378.852 us; speedup 1.0000x reference)
//
#include <hip/hip_runtime.h>
#include <hip/hip_bf16.h>
#include <cstdint>
#include <cstddef>

#define BATCH 2
#define S_LEN 2048
#define HID   2048
#define NH    16
#define HD    128
#define GK    2048          // K of all projections
#define NT    (GK / 64)     // 32 K-tiles of 64
#define NIT   (NT / 2)      // 16 iterations, 2 K-tiles each
#define ATT_TILES (32 * NH * BATCH)   // 32 q-tiles x 32 (b,h) = 1024

typedef short bf16x8 __attribute__((ext_vector_type(8)));
typedef float f32x4  __attribute__((ext_vector_type(4)));

__device__ inline unsigned short f2bf(float f) {
    unsigned int u = __float_as_uint(f);
    unsigned int r = (u + 0x7fffu + ((u >> 16) & 1u)) >> 16;
    return (unsigned short)r;
}

// ---------------- fp32 -> bf16 convert, 8 elems/thread ----------------
__global__ __launch_bounds__(256) void conv_f32_bf16(const float* __restrict__ src,
                                                     unsigned short* __restrict__ dst,
                                                     long n) {
    long i = ((long)blockIdx.x * 256 + threadIdx.x) * 8;
    if (i >= n) return;
    const float4 a = *(const float4*)(src + i);
    const float4 b = *(const float4*)(src + i + 4);
    union { unsigned short u[8]; bf16x8 v; } o;
    o.u[0] = f2bf(a.x); o.u[1] = f2bf(a.y); o.u[2] = f2bf(a.z); o.u[3] = f2bf(a.w);
    o.u[4] = f2bf(b.x); o.u[5] = f2bf(b.y); o.u[6] = f2bf(b.z); o.u[7] = f2bf(b.w);
    *(bf16x8*)(dst + i) = o.v;
}

__global__ __launch_bounds__(256) void conv4_f32_bf16(const float* __restrict__ s0,
                                                      const float* __restrict__ s1,
                                                      const float* __restrict__ s2,
                                                      const float* __restrict__ s3,
                                                      unsigned short* __restrict__ d0,
                                                      unsigned short* __restrict__ d1,
                                                      unsigned short* __restrict__ d2,
                                                      unsigned short* __restrict__ d3,
                                                      long n) {
    const int z = blockIdx.y;
    const float* src = (z == 0) ? s0 : (z == 1) ? s1 : (z == 2) ? s2 : s3;
    unsigned short* dst = (z == 0) ? d0 : (z == 1) ? d1 : (z == 2) ? d2 : d3;
    long i = ((long)blockIdx.x * 256 + threadIdx.x) * 8;
    if (i >= n) return;
    const float4 a = *(const float4*)(src + i);
    const float4 b = *(const float4*)(src + i + 4);
    union { unsigned short u[8]; bf16x8 v; } o;
    o.u[0] = f2bf(a.x); o.u[1] = f2bf(a.y); o.u[2] = f2bf(a.z); o.u[3] = f2bf(a.w);
    o.u[4] = f2bf(b.x); o.u[5] = f2bf(b.y); o.u[6] = f2bf(b.z); o.u[7] = f2bf(b.w);
    *(bf16x8*)(dst + i) = o.v;
}

__global__ void zero_int(int* p) { *p = 0; }

// =====================================================================
// 256x128 GEMM, v2: 4-phase cross-phase-pipelined schedule.
// C = A(row-major MxK) . B^T (B row-major NxK).  BM=256, BN=128, BK=64.
// 512 threads = 8 waves (4M x 2N), per-wave output 64x64, acc[4][4].
// LDS 96 KiB: buf d at d*24576 (u16): A 256x64 @ +0, B 128x64 @ +16384.
//
// KEY CHANGE vs v1 (which measured MfmaUtil 37.6%): fragment ds_reads of
// phase P+1 are issued BEFORE phase P's MFMAs, with NO explicit
// lgkmcnt(0) -- the compiler emits counted lgkm waits at first use
// (next phase), overlapping LDS port time + latency with the matrix
// pipe.  LDS-read floor per K-tile (128KB @ ~85B/cy = 1500cy) now
// overlaps MFMA (1242cy) instead of adding to it.
//
// Phase plan per iter i (tiles 2i=buf0, 2i+1=buf1; phases = N-halves):
//   Ph0: MFMA aE*bA(h0,buf0) | read buf0.Bh1->bB   | stage T(2i+1).B->buf1.B
//   Ph1: MFMA aE*bB(h1,buf0) | read buf1.A->aO,
//        vmcnt(0) top        |      buf1.Bh0->bA   | stage T(2i+2).A->buf0.A
//   Ph2: MFMA aO*bA(h0,buf1) | read buf1.Bh1->bB   | stage T(2i+2).B->buf0.B
//   Ph3: MFMA aO*bB(h1,buf1) | read buf0'.A->aE,
//        vmcnt(0) top        |      buf0'.Bh0->bA  | stage T(2i+3).A->buf1.A
// Safety (all verified): every STAGE lands after the phase-top barrier
// that publishes completion of that region's frag reads; vmcnt(0) at
// Ph1/Ph3 tops drains exactly [prev A(4) + prev B(2)] = the tile whose
// frag reads issue in that phase.  4 barriers/iter (was 16).
// Swizzle: LDS[r][chunk16B c] holds global[r][c ^ (r&7)] (pre-swizzled
// source, linear global_load_lds dest); reads XOR back with ln&7.
// =====================================================================

#define STAGE(DU, SRC, KT, H) do {                                            \
    const unsigned short* _s0 = (SRC) + (size_t)((H) * 128) * GK + (KT) * 64; \
    __builtin_amdgcn_global_load_lds(                                         \
        (const __attribute__((address_space(1))) void*)_s0,                   \
        (__attribute__((address_space(3))) void*)(Sm + (DU) + (H) * 8192 + sdst), \
        16, 0, 0);                                                            \
    __builtin_amdgcn_global_load_lds(                                         \
        (const __attribute__((address_space(1))) void*)(_s0 + (size_t)64 * GK), \
        (__attribute__((address_space(3))) void*)(Sm + (DU) + (H) * 8192 + 4096 + sdst), \
        16, 0, 0);                                                            \
} while (0)

// A-full fragment read: 8 x ds_read_b128 into bank[4][2]
#define READ_AF(D, AB) do { _Pragma("unroll")                                 \
    for (int mi = 0; mi < 4; ++mi) {                                          \
        const int r_ = wm * 64 + mi * 16 + ln;                                \
        AB[mi][0] = *(const bf16x8*)&Sm[(D) * 24576 + r_ * 64 + sw0];         \
        AB[mi][1] = *(const bf16x8*)&Sm[(D) * 24576 + r_ * 64 + sw1];         \
    } } while (0)

// B half-fragment read: 4 x ds_read_b128 into bank[2][2]
#define READ_BH(D, BB, HH) do { _Pragma("unroll")                             \
    for (int ni = 0; ni < 2; ++ni) {                                          \
        const int r_ = wn * 64 + ((HH) * 2 + ni) * 16 + ln;                   \
        BB[ni][0] = *(const bf16x8*)&Sm[(D) * 24576 + 16384 + r_ * 64 + sw0]; \
        BB[ni][1] = *(const bf16x8*)&Sm[(D) * 24576 + 16384 + r_ * 64 + sw1]; \
    } } while (0)

// 16 MFMAs: all 4 m-frags x one N-half x 2 k-slices
#define MFMA_H(AB, BB, HH) do { _Pragma("unroll")                             \
    for (int mi = 0; mi < 4; ++mi) _Pragma("unroll")                          \
    for (int ni = 0; ni < 2; ++ni) _Pragma("unroll")                          \
    for (int ks = 0; ks < 2; ++ks)                                            \
        acc[mi][(HH)*2+ni] = __builtin_amdgcn_mfma_f32_16x16x32_bf16(         \
            AB[mi][ks], BB[ni][ks], acc[mi][(HH)*2+ni], 0, 0, 0);             \
} while (0)

#define PRIO1 __builtin_amdgcn_s_setprio(1)
#define PRIO0 __builtin_amdgcn_s_setprio(0)
#define BAR   __builtin_amdgcn_s_barrier()
#define VM0   asm volatile("s_waitcnt vmcnt(0)" ::: "memory")

// mode 0: bf16 -> [b,h,s,d]; mode 1: bf16 -> [b,h,d,s] (LDS repack);
// mode 2: fp32 -> [m][HID]
__device__ __forceinline__ void gemm256_core(const unsigned short* __restrict__ A,
                                             const unsigned short* __restrict__ Bw,
                                             const float* __restrict__ bias,
                                             void* __restrict__ Cout,
                                             int mode, int M0, int N0,
                                             unsigned short* Sm) {
    const int tid  = threadIdx.x;
    const int lane = tid & 63;
    const int wave = tid >> 6;
    const int ln = lane & 15, g = lane >> 4;
    const int wm = wave & 3, wn = wave >> 2;

    const int strow = tid >> 3;
    const int stcol = (((tid & 7) ^ ((tid >> 3) & 7)) << 3);
    const unsigned short* gA = A  + (size_t)(M0 + strow) * GK + stcol;
    const unsigned short* gB = Bw + (size_t)(N0 + strow) * GK + stcol;
    const int sdst = wave * 512;

    const int sw0 = ((g    ) ^ (ln & 7)) << 3;
    const int sw1 = ((g + 4) ^ (ln & 7)) << 3;

    f32x4 acc[4][4];
#pragma unroll
    for (int i = 0; i < 4; ++i)
#pragma unroll
        for (int j = 0; j < 4; ++j) acc[i][j] = (f32x4){0.f, 0.f, 0.f, 0.f};
    bf16x8 aE[4][2], aO[4][2], bA[2][2], bB[2][2];

    // prologue: stage T0.A, T0.B, T1.A; drain T0; prime Ph0 fragments
    STAGE(0,     gA, 0, 0); STAGE(0,     gA, 0, 1);   // T0.A  (4 loads)
    STAGE(16384, gB, 0, 0);                            // T0.B  (2 loads)
    STAGE(24576, gA, 1, 0); STAGE(24576, gA, 1, 1);    // T1.A  (4 loads)
    asm volatile("s_waitcnt vmcnt(4)" ::: "memory");   // drain T0 (leave T1.A)
    BAR;
    READ_AF(0, aE); READ_BH(0, bA, 0);                 // Ph0 frags in flight

    for (int it = 0; it < NIT; ++it) {
        const int kt1 = 2 * it + 1;                                // odd tile (no clamp needed)
        const int kt2 = (2 * it + 2 < NT) ? 2 * it + 2 : NT - 1;   // tail clamp: never read
        const int kt3 = (2 * it + 3 < NT) ? 2 * it + 3 : NT - 1;
        // ---- Ph0: compute buf0 x Bh0 ----
        BAR;                                   // buf1.B readers done (prev iter)
        STAGE(24576 + 16384, gB, kt1, 0);      // o.B -> buf1.B
        READ_BH(0, bB, 1);                     // buf0.Bh1 frags (for Ph1)
        PRIO1; MFMA_H(aE, bA, 0); PRIO0;
        // ---- Ph1: compute buf0 x Bh1 ----
        VM0;                                   // drain [T1.A(prev Ph3), o.B(Ph0)]
        BAR;                                   // publish -> buf1 readable; buf0.A free
        STAGE(0, gA, kt2, 0); STAGE(0, gA, kt2, 1);   // e.A -> buf0.A
        READ_AF(1, aO); READ_BH(1, bA, 0);     // buf1 frags (for Ph2)
        PRIO1; MFMA_H(aE, bB, 1); PRIO0;
        // ---- Ph2: compute buf1 x Bh0 ----
        BAR;                                   // buf0.B readers done
        STAGE(16384, gB, kt2, 0);              // e.B -> buf0.B
        READ_BH(1, bB, 1);                     // buf1.Bh1 frags (for Ph3)
        PRIO1; MFMA_H(aO, bA, 0); PRIO0;
        // ---- Ph3: compute buf1 x Bh1 ----
        VM0;                                   // drain [e.A(Ph1), e.B(Ph2)]
        BAR;                                   // publish -> buf0 readable; buf1.A free
        STAGE(24576, gA, kt3, 0); STAGE(24576, gA, kt3, 1);  // o'.A -> buf1.A
        READ_AF(0, aE); READ_BH(0, bA, 0);     // buf0' frags (for next Ph0)
        PRIO1; MFMA_H(aO, bB, 1); PRIO0;
    }
    asm volatile("s_waitcnt vmcnt(0)" ::: "memory");  // drain tail prefetches before LDS reuse
    __syncthreads();

    if (mode == 0) {
        // bf16 -> [b, h, s, d]; BN=128 = exactly one head per block
        const int bb = M0 >> 11;
        const int sb = M0 & (S_LEN - 1);
        const int h  = N0 >> 7;
#pragma unroll
        for (int nf = 0; nf < 4; ++nf) {
            const int d = wn * 64 + nf * 16 + ln;
            const float bn = bias[N0 + d];
            unsigned short* dst = (unsigned short*)Cout +
                (((size_t)(bb * NH + h) * S_LEN + sb + wm * 64) * HD + d);
#pragma unroll
            for (int mf = 0; mf < 4; ++mf)
#pragma unroll
                for (int r = 0; r < 4; ++r)
                    dst[(size_t)(mf * 16 + g * 4 + r) * HD] = f2bf(acc[mf][nf][r] + bn);
        }
    } else if (mode == 2) {
        float* dst = (float*)Cout;
#pragma unroll
        for (int nf = 0; nf < 4; ++nf) {
            const int n = N0 + wn * 64 + nf * 16 + ln;
            const float bn = bias[n];
#pragma unroll
            for (int mf = 0; mf < 4; ++mf)
#pragma unroll
                for (int r = 0; r < 4; ++r) {
                    const int m = M0 + wm * 64 + mf * 16 + g * 4 + r;
                    dst[(size_t)m * HID + n] = acc[mf][nf][r] + bn;
                }
        }
    } else {
        // mode 1: bf16 -> [b, h, d, s].  Two s-half passes (128 rows each)
        // through LDS [128 d][128 s] u16, chunk swizzle cs = (s>>3)^(d&15).
        const int bb = M0 >> 11;
        const int sb = M0 & (S_LEN - 1);
        const int h  = N0 >> 7;
#pragma unroll
        for (int p = 0; p < 2; ++p) {
            if ((wm >> 1) == p) {      // waves owning rows p*128..p*128+127
#pragma unroll
                for (int nf = 0; nf < 4; ++nf) {
                    const int dl = wn * 64 + nf * 16 + ln;        // 0..127
                    const float bn = bias[N0 + dl];
#pragma unroll
                    for (int mf = 0; mf < 4; ++mf) {
                        const int sl = (wm & 1) * 64 + mf * 16 + g * 4;  // 0..127 in half
                        const int cs = (sl >> 3) ^ (dl & 15);
                        union { unsigned short u[4]; unsigned long long q; } pk;
#pragma unroll
                        for (int r = 0; r < 4; ++r) pk.u[r] = f2bf(acc[mf][nf][r] + bn);
                        *(unsigned long long*)&Sm[dl * 128 + cs * 8 + (sl & 7)] = pk.q;
                    }
                }
            }
            __syncthreads();
            {
                const int dl = tid >> 2;          // 0..127
                unsigned short* dst = (unsigned short*)Cout +
                    ((size_t)(bb * NH + h) * HD + dl) * S_LEN + sb + p * 128;
#pragma unroll
                for (int jj = 0; jj < 4; ++jj) {
                    const int sc = (tid & 3) + jj * 4;   // 16 chunks -> 128 s
                    const int cs = sc ^ (dl & 15);
                    *(bf16x8*)(dst + sc * 8) = *(const bf16x8*)&Sm[dl * 128 + cs * 8];
                }
            }
            __syncthreads();
        }
    }
}

__global__ __launch_bounds__(512, 2) void gemm_qkv256(
        const unsigned short* __restrict__ A,
        const unsigned short* __restrict__ w0, const unsigned short* __restrict__ w1,
        const unsigned short* __restrict__ w2,
        const float* __restrict__ b0, const float* __restrict__ b1,
        const float* __restrict__ b2,
        void* o0, void* o1, void* o2) {
    extern __shared__ __align__(16) unsigned short Sm[];
    const int z = blockIdx.z;
    const unsigned short* Bw = (z == 0) ? w0 : (z == 1) ? w1 : w2;
    const float* bias = (z == 0) ? b0 : (z == 1) ? b1 : b2;
    void* Cout = (z == 0) ? o0 : (z == 1) ? o1 : o2;
    gemm256_core(A, Bw, bias, Cout, (z == 2) ? 1 : 0,
                 blockIdx.y * 256, blockIdx.x * 128, Sm);
}

__global__ __launch_bounds__(512, 2) void gemm_out256(
        const unsigned short* __restrict__ A, const unsigned short* __restrict__ Bw,
        const float* __restrict__ bias, float* __restrict__ Cout) {
    extern __shared__ __align__(16) unsigned short Sm[];
    gemm256_core(A, Bw, bias, Cout, 2, blockIdx.y * 256, blockIdx.x * 128, Sm);
}

// ---------------- causal flash attention (unchanged this round: control) ----
// Q,K: [B,NH,S,HD] bf16 ; Vt: [B,NH,HD,S] bf16 ; O: [B,S,HID] bf16
__global__ __launch_bounds__(256, 2) void attn_kernel(const unsigned short* __restrict__ Q,
                                                      const unsigned short* __restrict__ Kk,
                                                      const unsigned short* __restrict__ Vt,
                                                      unsigned short* __restrict__ O,
                                                      int* __restrict__ ticket) {
    __shared__ __align__(16) unsigned short Ks[2 * 64 * 128];  // [buf][key][d], chunk^=(key&15)
    __shared__ __align__(16) unsigned short Vs[2 * 128 * 64];  // [buf][d][key], chunk^=(d&7)
    __shared__ __align__(16) unsigned short Pl[4][16 * 72];    // per-wave P, stride 72
    __shared__ int tsh;
    const int tid = threadIdx.x;
    const int lane = tid & 63;
    const int wave = tid >> 6;
    const int g = lane >> 4, ln = lane & 15;
    const float scale2 = 0.08838834764831845f * 1.4426950408889634f;  // 1/sqrt(128)*log2(e)
    const bf16x8 ones_v = {0x3F80, 0x3F80, 0x3F80, 0x3F80, 0x3F80, 0x3F80, 0x3F80, 0x3F80};

    const int kcol = ((tid & 15) ^ ((tid >> 4) & 15)) * 8;   // K: 16 chunks/row
    const int vcol = ((tid & 7) ^ ((tid >> 3) & 7)) * 8;     // V: 8 chunks/row

    for (;;) {
        if (tid == 0) tsh = atomicAdd(ticket, 1);
        __syncthreads();
        const int t = tsh;
        if (t >= ATT_TILES) break;
        const int qt = 31 - (t >> 5);       // LPT: big q-tiles first
        const int bh = t & 31;
        const int qbase = qt * 64 + wave * 16;

        const unsigned short* Qp = Q  + (size_t)bh * S_LEN * HD;
        const unsigned short* Kp = Kk + (size_t)bh * S_LEN * HD;
        const unsigned short* Vp = Vt + (size_t)bh * HD * S_LEN;

        bf16x8 aq[4];
#pragma unroll
        for (int dc = 0; dc < 4; ++dc)
            aq[dc] = *(const bf16x8*)&Qp[(size_t)(qbase + ln) * HD + dc * 32 + g * 8];

        f32x4 acc[9];
#pragma unroll
        for (int i = 0; i < 9; ++i) acc[i] = (f32x4){0.f, 0.f, 0.f, 0.f};

        // prologue: stage tile 0 -> buf0
#pragma unroll
        for (int i = 0; i < 4; ++i) {
            const unsigned short* gk = Kp + (size_t)(i * 16 + (tid >> 4)) * HD + kcol;
            __builtin_amdgcn_global_load_lds(
                (const __attribute__((address_space(1))) void*)gk,
                (__attribute__((address_space(3))) void*)(Ks + i * 2048 + wave * 512),
                16, 0, 0);
        }
#pragma unroll
        for (int i = 0; i < 4; ++i) {
            const unsigned short* gv = Vp + (size_t)(i * 32 + (tid >> 3)) * S_LEN + vcol;
            __builtin_amdgcn_global_load_lds(
                (const __attribute__((address_space(1))) void*)gv,
                (__attribute__((address_space(3))) void*)(Vs + i * 2048 + wave * 512),
                16, 0, 0);
        }

        for (int kt = 0; kt <= qt; ++kt) {
            const int cur = kt & 1;
            const bool do_stage = (kt + 1 <= qt);
            if (do_stage) {
                const int kb2 = (kt + 1) * 64;
                const int nb  = (kt + 1) & 1;
                unsigned short* kdst = Ks + nb * 8192 + wave * 512;
                unsigned short* vdst = Vs + nb * 8192 + wave * 512;
#pragma unroll
                for (int i = 0; i < 4; ++i) {
                    const unsigned short* gk = Kp + (size_t)(kb2 + i * 16 + (tid >> 4)) * HD + kcol;
                    __builtin_amdgcn_global_load_lds(
                        (const __attribute__((address_space(1))) void*)gk,
                        (__attribute__((address_space(3))) void*)(kdst + i * 2048),
                        16, 0, 0);
                }
#pragma unroll
                for (int i = 0; i < 4; ++i) {
                    const unsigned short* gv = Vp + (size_t)(i * 32 + (tid >> 3)) * S_LEN + kb2 + vcol;
                    __builtin_amdgcn_global_load_lds(
                        (const __attribute__((address_space(1))) void*)gv,
                        (__attribute__((address_space(3))) void*)(vdst + i * 2048),
                        16, 0, 0);
                }
            }
            if (kt == 0 || !do_stage) {
                asm volatile("s_waitcnt vmcnt(0)" ::: "memory");
            } else {
                asm volatile("s_waitcnt vmcnt(8)" ::: "memory");
            }
            __builtin_amdgcn_s_barrier();

            const int kbuf = cur * 8192;
            f32x4 sc[4];
            __builtin_amdgcn_s_setprio(1);
#pragma unroll
            for (int nc = 0; nc < 4; ++nc) {
                sc[nc] = (f32x4){0.f, 0.f, 0.f, 0.f};
#pragma unroll
                for (int dc = 0; dc < 4; ++dc) {
                    bf16x8 bk = *(const bf16x8*)&Ks[kbuf + (nc * 16 + ln) * 128 + ((dc * 4 + g) ^ ln) * 8];
                    sc[nc] = __builtin_amdgcn_mfma_f32_16x16x32_bf16(aq[dc], bk, sc[nc], 0, 0, 0);
                }
            }
            __builtin_amdgcn_s_setprio(0);
            const bool diag = (kt == qt);
#pragma unroll
            for (int nc = 0; nc < 4; ++nc)
#pragma unroll
                for (int r = 0; r < 4; ++r) {
                    float pv = __builtin_amdgcn_exp2f(sc[nc][r] * scale2);
                    if (diag && (nc * 16 + ln > wave * 16 + g * 4 + r)) pv = 0.f;
                    Pl[wave][(g * 4 + r) * 72 + nc * 16 + ln] = f2bf(pv);
                }
            __builtin_amdgcn_s_setprio(1);
#pragma unroll
            for (int kc = 0; kc < 2; ++kc) {
                bf16x8 ap = *(const bf16x8*)&Pl[wave][ln * 72 + kc * 32 + g * 8];
#pragma unroll
                for (int d2 = 0; d2 < 8; ++d2) {
                    bf16x8 bv = *(const bf16x8*)&Vs[kbuf + (d2 * 16 + ln) * 64 + ((kc * 4 + g) ^ (ln & 7)) * 8];
                    acc[d2] = __builtin_amdgcn_mfma_f32_16x16x32_bf16(ap, bv, acc[d2], 0, 0, 0);
                }
                acc[8] = __builtin_amdgcn_mfma_f32_16x16x32_bf16(ap, ones_v, acc[8], 0, 0, 0);
            }
            __builtin_amdgcn_s_setprio(0);
            __builtin_amdgcn_s_barrier();
        }
        const int b = bh >> 4, h = bh & 15;
        float inv[4];
#pragma unroll
        for (int r = 0; r < 4; ++r) inv[r] = 1.0f / acc[8][r];
#pragma unroll
        for (int d2 = 0; d2 < 8; ++d2)
#pragma unroll
            for (int r = 0; r < 4; ++r) {
                const int row = qbase + g * 4 + r;
                const int col = h * HD + d2 * 16 + ln;
                O[((size_t)b * S_LEN + row) * HID + col] = f2bf(acc[d2][r] * inv[r]);
            }
    }
}

extern "C" void kernel_launch(void* const* d_in, const int* in_sizes, int n_in,
                              void* d_out, int out_size, void* d_ws, size_t ws_size,
                              hipStream_t stream) {
    const float* x  = (const float*)d_in[0];
    const float* wq = (const float*)d_in[1];
    const float* bq = (const float*)d_in[2];
    const float* wk = (const float*)d_in[3];
    const float* bk = (const float*)d_in[4];
    const float* wv = (const float*)d_in[5];
    const float* bv = (const float*)d_in[6];
    const float* wo = (const float*)d_in[7];
    const float* bo = (const float*)d_in[8];
    float* out = (float*)d_out;

    const long nx = (long)BATCH * S_LEN * HID;  // 8388608
    const long nw = (long)HID * HID;            // 4194304

    char* p = (char*)d_ws;
    unsigned short* xb  = (unsigned short*)p; p += nx * 2;
    unsigned short* wqb = (unsigned short*)p; p += nw * 2;
    unsigned short* wkb = (unsigned short*)p; p += nw * 2;
    unsigned short* wvb = (unsigned short*)p; p += nw * 2;
    unsigned short* wob = (unsigned short*)p; p += nw * 2;
    unsigned short* Qb  = (unsigned short*)p; p += nx * 2;
    unsigned short* Kb  = (unsigned short*)p; p += nx * 2;
    unsigned short* Vtb = (unsigned short*)p; p += nx * 2;
    unsigned short* Ob  = (unsigned short*)p; p += nx * 2;
    int* ticket = (int*)p;

    conv_f32_bf16<<<(int)(nx / 8 / 256), 256, 0, stream>>>(x, xb, nx);
    dim3 cgrid((unsigned)(nw / 8 / 256), 4);
    conv4_f32_bf16<<<cgrid, 256, 0, stream>>>(wq, wk, wv, wo, wqb, wkb, wvb, wob, nw);
    zero_int<<<1, 1, 0, stream>>>(ticket);

    const int M = BATCH * S_LEN;  // 4096
    dim3 qkvgrid(HID / 128, M / 256, 3);   // 16 x 16 x 3 = 768 blocks (3 rounds)
    gemm_qkv256<<<qkvgrid, 512, 98304, stream>>>(xb, wqb, wkb, wvb, bq, bk, bv,
                                                 Qb, Kb, Vtb);

    attn_kernel<<<512, 256, 0, stream>>>(Qb, Kb, Vtb, Ob, ticket);

    dim3 ogrid(HID / 128, M / 256);        // 16 x 16 = 256 blocks (1 round)
    gemm_out256<<<ogrid, 512, 98304, stream>>>(Ob, wob, bo, out);
}